// Round 12
// baseline (329.219 us; speedup 1.0000x reference)
//
#include <hip/hip_runtime.h>
#include <hip/hip_bf16.h>

// B=8, C=512, N=2048, P=256.
// Round 12: fused attention v4 — split-K ACROSS BLOCKS (deterministic).
//   v3's intra-block wave merge raced + direct-global PV B-loads were slow.
//   v4: 512 blocks = 2 key-halves x 32 q-tiles x 8 batches; each block is the
//   PROVEN R10 kernel limited to its 8 key-tiles, writing fp32 partials
//   (O, m, l) to global; a small merge_y kernel does the flash merge.
//   LDS cut 91->74.8 KB (phi staged in 32k chunks) -> 2 blocks/CU resident
//   -> 2 waves/SIMD (R10 was structurally stuck at 1).
// Numerics: theta/phi/scores split-bf16 (3 MFMAs, fp32-class logits);
//           g, P, y, z plain bf16 (post-softmax, not exp-amplified).

typedef __attribute__((ext_vector_type(8))) short short8;
typedef __attribute__((ext_vector_type(4))) float floatx4;

// ---------------- bf16 helpers ----------------
__device__ __forceinline__ unsigned short f2bf(float v) {
    __hip_bfloat16 h = __float2bfloat16(v);
    return *(unsigned short*)&h;
}
__device__ __forceinline__ float bf2f(unsigned short u) {
    __hip_bfloat16 h;
    *(unsigned short*)&h = u;
    return __bfloat162float(h);
}

// transpose + hi/lo split: X [R][N] fp32 -> Thi/Tlo [N][R] bf16 (batched over z)
__global__ __launch_bounds__(256) void transpose_split(
    const float* __restrict__ X, unsigned short* __restrict__ Thi,
    unsigned short* __restrict__ Tlo, int R, int N)
{
    X   += (long)blockIdx.z * R * N;
    Thi += (long)blockIdx.z * N * R;
    Tlo += (long)blockIdx.z * N * R;
    __shared__ float s[32][33];
    const int tx = threadIdx.x & 31, ty = threadIdx.x >> 5;
    const int n0 = blockIdx.x * 32, r0 = blockIdx.y * 32;
#pragma unroll
    for (int r = 0; r < 4; ++r)
        s[ty + r * 8][tx] = X[(long)(r0 + ty + r * 8) * N + n0 + tx];
    __syncthreads();
#pragma unroll
    for (int r = 0; r < 4; ++r) {
        const int n = ty + r * 8;
        const float v = s[tx][n];
        const unsigned short hi = f2bf(v);
        const unsigned short lo = f2bf(v - bf2f(hi));
        Thi[(long)(n0 + n) * R + r0 + tx] = hi;
        Tlo[(long)(n0 + n) * R + r0 + tx] = lo;
    }
}

// concat [Wth; Wph] rows and hi/lo split: out [2P][C]
__global__ __launch_bounds__(256) void split_w2(
    const float* __restrict__ Wth, const float* __restrict__ Wph,
    unsigned short* __restrict__ Whi, unsigned short* __restrict__ Wlo, int PC)
{
    const int i = blockIdx.x * 256 + threadIdx.x;
    if (i < 2 * PC) {
        const float v = (i < PC) ? Wth[i] : Wph[i - PC];
        const unsigned short hi = f2bf(v);
        Whi[i] = hi;
        Wlo[i] = f2bf(v - bf2f(hi));
    }
}

__global__ __launch_bounds__(256) void cast_bf16(
    const float* __restrict__ X, unsigned short* __restrict__ Y)
{
    const long i = ((long)blockIdx.x * 256 + threadIdx.x) * 4;
    const float4 v = *(const float4*)&X[i];
    ushort4 o;
    o.x = f2bf(v.x); o.y = f2bf(v.y); o.z = f2bf(v.z); o.w = f2bf(v.w);
    *(ushort4*)&Y[i] = o;
}

// ---------------- MFMA GEMM (register-prefetch pipeline, round 7) ----------------
#define BK 32

template <bool SPLIT, int OUTMODE, int FM, int FN>
__global__ __launch_bounds__(256) void mfma_gemm(
    const unsigned short* __restrict__ Ahi, const unsigned short* __restrict__ Alo,
    const unsigned short* __restrict__ Bhi, const unsigned short* __restrict__ Blo,
    void* __restrict__ Cout, void* __restrict__ Cout2,
    int K, int lda, int ldb, int ldc,
    long sA, long sB, long sC,
    float* __restrict__ S1, float* __restrict__ S2)
{
    constexpr int MTM = FM * 32, MTN = FN * 32;
    constexpr int SA = FM / 2, SB = FN / 2;

    Ahi += (long)blockIdx.z * sA;
    Bhi += (long)blockIdx.z * sB;
    if (SPLIT) { Alo += (long)blockIdx.z * sA; Blo += (long)blockIdx.z * sB; }
    float* Cf = (float*)Cout + (long)blockIdx.z * sC;
    unsigned short* Ch = (unsigned short*)Cout + (long)blockIdx.z * sC;
    unsigned short* Cl = (unsigned short*)Cout2 + (long)blockIdx.z * sC;

    __shared__ unsigned short AsH[MTM * BK], BsH[MTN * BK];
    __shared__ unsigned short AsL[SPLIT ? MTM * BK : 8], BsL[SPLIT ? MTN * BK : 8];

    const int tid = threadIdx.x;
    const int wid = tid >> 6, lane = tid & 63;
    const int wm = (wid >> 1) * (FM * 16), wn = (wid & 1) * (FN * 16);
    const int l15 = lane & 15, quad = lane >> 4;
    const int m0 = blockIdx.y * MTM, n0 = blockIdx.x * MTN;

    int arow[SA], acol[SA], brow[SB], bcol[SB];
#pragma unroll
    for (int t = 0; t < SA; ++t) {
        const int gid = t * 256 + tid;
        arow[t] = gid >> 2; acol[t] = (gid & 3) * 8;
    }
#pragma unroll
    for (int t = 0; t < SB; ++t) {
        const int gid = t * 256 + tid;
        brow[t] = gid >> 2; bcol[t] = (gid & 3) * 8;
    }

    short8 pa[SA], pb[SB], paL[SPLIT ? SA : 1], pbL[SPLIT ? SB : 1];

    auto loadTiles = [&](int k0) {
#pragma unroll
        for (int t = 0; t < SA; ++t) {
            const long o = (long)(m0 + arow[t]) * lda + k0 + acol[t];
            pa[t] = *(const short8*)&Ahi[o];
            if (SPLIT) paL[t] = *(const short8*)&Alo[o];
        }
#pragma unroll
        for (int t = 0; t < SB; ++t) {
            const long o = (long)(n0 + brow[t]) * ldb + k0 + bcol[t];
            pb[t] = *(const short8*)&Bhi[o];
            if (SPLIT) pbL[t] = *(const short8*)&Blo[o];
        }
    };
    auto writeTiles = [&]() {
#pragma unroll
        for (int t = 0; t < SA; ++t) {
            *(short8*)&AsH[arow[t] * BK + acol[t]] = pa[t];
            if (SPLIT) *(short8*)&AsL[arow[t] * BK + acol[t]] = paL[t];
        }
#pragma unroll
        for (int t = 0; t < SB; ++t) {
            *(short8*)&BsH[brow[t] * BK + bcol[t]] = pb[t];
            if (SPLIT) *(short8*)&BsL[brow[t] * BK + bcol[t]] = pbL[t];
        }
    };

    floatx4 acc[FM][FN];
#pragma unroll
    for (int i = 0; i < FM; ++i)
#pragma unroll
        for (int j = 0; j < FN; ++j) acc[i][j] = (floatx4){0.f, 0.f, 0.f, 0.f};

    const int iters = K / BK;
    loadTiles(0);
    writeTiles();
    __syncthreads();

    for (int it = 0; it < iters; ++it) {
        if (it + 1 < iters) loadTiles((it + 1) * BK);

        short8 ah[FM], bh[FN], al[SPLIT ? FM : 1], bl[SPLIT ? FN : 1];
#pragma unroll
        for (int i = 0; i < FM; ++i) {
            ah[i] = *(const short8*)&AsH[(wm + i * 16 + l15) * BK + quad * 8];
            if (SPLIT) al[i] = *(const short8*)&AsL[(wm + i * 16 + l15) * BK + quad * 8];
        }
#pragma unroll
        for (int j = 0; j < FN; ++j) {
            bh[j] = *(const short8*)&BsH[(wn + j * 16 + l15) * BK + quad * 8];
            if (SPLIT) bl[j] = *(const short8*)&BsL[(wn + j * 16 + l15) * BK + quad * 8];
        }
#pragma unroll
        for (int i = 0; i < FM; ++i)
#pragma unroll
            for (int j = 0; j < FN; ++j) {
                acc[i][j] = __builtin_amdgcn_mfma_f32_16x16x32_bf16(ah[i], bh[j], acc[i][j], 0, 0, 0);
                if (SPLIT) {
                    acc[i][j] = __builtin_amdgcn_mfma_f32_16x16x32_bf16(ah[i], bl[j], acc[i][j], 0, 0, 0);
                    acc[i][j] = __builtin_amdgcn_mfma_f32_16x16x32_bf16(al[i], bh[j], acc[i][j], 0, 0, 0);
                }
            }

        if (it + 1 < iters) {
            __syncthreads();
            writeTiles();
            __syncthreads();
        }
    }

#pragma unroll
    for (int i = 0; i < FM; ++i)
#pragma unroll
        for (int j = 0; j < FN; ++j) {
            const int m = m0 + wm + i * 16 + quad * 4;
            const int n = n0 + wn + j * 16 + l15;
#pragma unroll
            for (int r = 0; r < 4; ++r) {
                const float v = acc[i][j][r];
                const long idx = (long)(m + r) * ldc + n;
                if (OUTMODE == 0) {
                    Cf[idx] = v;
                } else if (OUTMODE == 1 || OUTMODE == 3) {
                    Ch[idx] = f2bf(v);
                } else {
                    const unsigned short hi = f2bf(v);
                    Ch[idx] = hi;
                    Cl[idx] = f2bf(v - bf2f(hi));
                }
            }
        }

    if (OUTMODE == 3) {
        const int slot = (blockIdx.z * gridDim.x + blockIdx.x) * 2 + (wn >> 6);
#pragma unroll
        for (int i = 0; i < FM; ++i)
#pragma unroll
            for (int r = 0; r < 4; ++r) {
                float s = 0.f, q = 0.f;
#pragma unroll
                for (int j = 0; j < FN; ++j) {
                    const float v = acc[i][j][r];
                    s += v; q += v * v;
                }
#pragma unroll
                for (int msk = 1; msk < 16; msk <<= 1) {
                    s += __shfl_xor(s, msk, 64);
                    q += __shfl_xor(q, msk, 64);
                }
                if (l15 == 0) {
                    const int row = m0 + wm + i * 16 + quad * 4 + r;
                    S1[(long)row * 256 + slot] = s;
                    S2[(long)row * 256 + slot] = q;
                }
            }
    }
}

// ---------------- fused scores+softmax+y v4 (block split-K) ----------------
// 512 blocks x 256 threads: b = id&7, qt = (id>>3)&31, half = id>>8.
// Each block = R10 kernel over key-tiles [half*8, half*8+8), 4 waves x 16 q.
// Writes fp32 partials (O, m, l) per half; merge_y combines (deterministic).
#define FSTR4 40    // phi LDS row stride (32 k + 8 pad)
#define GSTR 72     // G LDS row stride (64 keys + 8 pad)
#define PSTRP 136   // P LDS row stride (128 keys + 8 pad)

__global__ __launch_bounds__(256) void fused_attn(
    const unsigned short* __restrict__ thphH,
    const unsigned short* __restrict__ thphL,
    const unsigned short* __restrict__ gbf,
    float* __restrict__ Opart,      // [2][B*N][P]
    float* __restrict__ Mpart,      // [2][B*N]
    float* __restrict__ Lpart)      // [2][B*N]
{
    const int N = 2048, P = 256, P2 = 512;
    const long BN = 8L * 2048;
    const int id = blockIdx.x;
    const int b    = id & 7;
    const int qt   = (id >> 3) & 31;
    const int half = id >> 8;
    const int q0 = qt * 64;

    const unsigned short* thB = thphH + (long)b * N * P2;
    const unsigned short* tlB = thphL + (long)b * N * P2;
    const unsigned short* gB  = gbf   + (long)b * P * N;
    float* Oh = Opart + (long)half * BN * P;
    float* Mh = Mpart + (long)half * BN;
    float* Lh = Lpart + (long)half * BN;

    __shared__ unsigned short Fh[128 * FSTR4], Fl[128 * FSTR4];  // phi 32k chunk
    __shared__ unsigned short Gs[256 * GSTR];                    // G 64-key chunk
    __shared__ unsigned short Pw[4][16 * PSTRP];                 // wave-private P

    const int tid = threadIdx.x;
    const int wid = tid >> 6, lane = tid & 63;
    const int l15 = lane & 15, quad = lane >> 4;

    // theta fragments in registers: wave rows [q0+wid*16, +16), A m = l15
    short8 tHr[8], tLr[8];
    {
        const unsigned short* t1 = thB + (long)(q0 + wid * 16 + l15) * P2;
        const unsigned short* t2 = tlB + (long)(q0 + wid * 16 + l15) * P2;
#pragma unroll
        for (int kt = 0; kt < 8; ++kt) {
            tHr[kt] = *(const short8*)&t1[kt * 32 + quad * 8];
            tLr[kt] = *(const short8*)&t2[kt * 32 + quad * 8];
        }
    }

    float mrun[4], lrun[4];
#pragma unroll
    for (int r = 0; r < 4; ++r) { mrun[r] = -1e30f; lrun[r] = 0.f; }

    floatx4 oacc[16];
#pragma unroll
    for (int p = 0; p < 16; ++p) oacc[p] = (floatx4){0.f, 0.f, 0.f, 0.f};

    // phi staging: 128 rows x 32 shorts -> 512 segs of 8 / 256 thr = 2 each
    short8 pfH[2], pfL[2], pg[8];
    const int grow = tid >> 3, gc8 = (tid & 7) * 8;   // G staging role

    auto loadPhi = [&](int m0, int kc) {
#pragma unroll
        for (int s = 0; s < 2; ++s) {
            const int gid = s * 256 + tid;
            const long o = (long)(m0 + (gid >> 2)) * P2 + P + kc * 32 + (gid & 3) * 8;
            pfH[s] = *(const short8*)&thB[o];
            pfL[s] = *(const short8*)&tlB[o];
        }
    };
    auto writePhi = [&]() {
#pragma unroll
        for (int s = 0; s < 2; ++s) {
            const int gid = s * 256 + tid;
            const int lo = (gid >> 2) * FSTR4 + (gid & 3) * 8;
            *(short8*)&Fh[lo] = pfH[s];
            *(short8*)&Fl[lo] = pfL[s];
        }
    };
    auto loadG = [&](int m0, int mc) {
#pragma unroll
        for (int s = 0; s < 8; ++s)
            pg[s] = *(const short8*)&gB[(long)(grow + s * 32) * N + m0 + mc * 64 + gc8];
    };
    auto writeG = [&]() {
#pragma unroll
        for (int s = 0; s < 8; ++s)
            *(short8*)&Gs[(grow + s * 32) * GSTR + gc8] = pg[s];
    };

    for (int mt = half * 8; mt < half * 8 + 8; ++mt) {
        const int m0 = mt * 128;

        // ---- S phase: 8 chunks of 32 k ----
        floatx4 sacc[8];
#pragma unroll
        for (int j = 0; j < 8; ++j) sacc[j] = (floatx4){0.f, 0.f, 0.f, 0.f};

        loadPhi(m0, 0);
        writePhi();
        __syncthreads();
#pragma unroll
        for (int kc = 0; kc < 8; ++kc) {
            if (kc < 7) loadPhi(m0, kc + 1);       // prefetch flies over MFMAs
            const short8 aH = tHr[kc];
            const short8 aL = tLr[kc];
#pragma unroll
            for (int j = 0; j < 8; ++j) {
                const int ro = (j * 16 + l15) * FSTR4 + quad * 8;
                const short8 bh = *(const short8*)&Fh[ro];
                const short8 bl = *(const short8*)&Fl[ro];
                sacc[j] = __builtin_amdgcn_mfma_f32_16x16x32_bf16(aH, bh, sacc[j], 0, 0, 0);
                sacc[j] = __builtin_amdgcn_mfma_f32_16x16x32_bf16(aH, bl, sacc[j], 0, 0, 0);
                sacc[j] = __builtin_amdgcn_mfma_f32_16x16x32_bf16(aL, bh, sacc[j], 0, 0, 0);
            }
            if (kc < 7) {
                __syncthreads();
                writePhi();                         // vmcnt wait lands here
                __syncthreads();
            }
        }

        // ---- online softmax (registers only; rows = quad*4+r) ----
        float alpha[4];
#pragma unroll
        for (int r = 0; r < 4; ++r) {
            float v = sacc[0][r];
#pragma unroll
            for (int j = 1; j < 8; ++j) v = fmaxf(v, sacc[j][r]);
            v = fmaxf(v, __shfl_xor(v, 1, 64));
            v = fmaxf(v, __shfl_xor(v, 2, 64));
            v = fmaxf(v, __shfl_xor(v, 4, 64));
            v = fmaxf(v, __shfl_xor(v, 8, 64));
            const float mo = mrun[r];
            const float mn = fmaxf(mo, v);
            mrun[r] = mn;
            alpha[r] = __expf(mo - mn);
        }
        float lpart[4] = {0.f, 0.f, 0.f, 0.f};
#pragma unroll
        for (int j = 0; j < 8; ++j)
#pragma unroll
            for (int r = 0; r < 4; ++r) {
                const float p = __expf(sacc[j][r] - mrun[r]);
                Pw[wid][(quad * 4 + r) * PSTRP + j * 16 + l15] = f2bf(p);
                lpart[r] += p;
            }
#pragma unroll
        for (int r = 0; r < 4; ++r) {
            float s = lpart[r];
            s += __shfl_xor(s, 1, 64);
            s += __shfl_xor(s, 2, 64);
            s += __shfl_xor(s, 4, 64);
            s += __shfl_xor(s, 8, 64);
            lrun[r] = lrun[r] * alpha[r] + s;
        }
#pragma unroll
        for (int p = 0; p < 16; ++p)
#pragma unroll
            for (int r = 0; r < 4; ++r) oacc[p][r] *= alpha[r];

        // ---- PV phase: G staged in 2 chunks of 64 keys ----
        loadG(m0, 0);
        writeG();
        __syncthreads();
#pragma unroll
        for (int mc = 0; mc < 2; ++mc) {
            if (mc == 0) loadG(m0, 1);             // prefetch
#pragma unroll
            for (int kk = 0; kk < 2; ++kk) {
                const short8 af = *(const short8*)&Pw[wid][l15 * PSTRP + mc * 64 + kk * 32 + quad * 8];
#pragma unroll
                for (int pj = 0; pj < 16; ++pj) {
                    const short8 bg = *(const short8*)&Gs[(pj * 16 + l15) * GSTR + kk * 32 + quad * 8];
                    oacc[pj] = __builtin_amdgcn_mfma_f32_16x16x32_bf16(af, bg, oacc[pj], 0, 0, 0);
                }
            }
            if (mc == 0) {
                __syncthreads();
                writeG();
                __syncthreads();
            }
        }
    }

    // ---- write fp32 partials (no normalization; merge_y does it) ----
    const long rbase = (long)b * N + q0 + wid * 16 + quad * 4;
#pragma unroll
    for (int pj = 0; pj < 16; ++pj)
#pragma unroll
        for (int r = 0; r < 4; ++r)
            Oh[(rbase + r) * P + pj * 16 + l15] = oacc[pj][r];
    if (l15 == 0) {
#pragma unroll
        for (int r = 0; r < 4; ++r) {
            Mh[rbase + r] = mrun[r];
            Lh[rbase + r] = lrun[r];
        }
    }
}

// flash merge of the two key-halves: y = (w0*O0 + w1*O1) / (w0*l0 + w1*l1)
__global__ __launch_bounds__(256) void merge_y(
    const float* __restrict__ Opart, const float* __restrict__ Mpart,
    const float* __restrict__ Lpart, unsigned short* __restrict__ ybf)
{
    const int P = 256;
    const long BN = 8L * 2048;
    const long row = (long)blockIdx.x * 8 + (threadIdx.x >> 5);
    const int c0 = (threadIdx.x & 31) * 8;
    const float m0 = Mpart[row], m1 = Mpart[BN + row];
    const float mm = fmaxf(m0, m1);
    const float w0 = __expf(m0 - mm), w1 = __expf(m1 - mm);
    const float linv = 1.0f / (Lpart[row] * w0 + Lpart[BN + row] * w1);
    const float* o0 = Opart + row * P + c0;
    const float* o1 = Opart + BN * P + row * P + c0;
    ushort4 outv[2];
#pragma unroll
    for (int h = 0; h < 2; ++h) {
        const float4 a = *(const float4*)&o0[h * 4];
        const float4 bq = *(const float4*)&o1[h * 4];
        outv[h].x = f2bf((a.x * w0 + bq.x * w1) * linv);
        outv[h].y = f2bf((a.y * w0 + bq.y * w1) * linv);
        outv[h].z = f2bf((a.z * w0 + bq.z * w1) * linv);
        outv[h].w = f2bf((a.w * w0 + bq.w * w1) * linv);
    }
    *(ushort4*)&ybf[row * P + c0] = outv[0];
    *(ushort4*)&ybf[row * P + c0 + 4] = outv[1];
}

// ---------------- BN finalize + apply ----------------
__global__ __launch_bounds__(256) void bn_finalize(
    const float* __restrict__ p1, const float* __restrict__ p2,
    float* __restrict__ mean, float* __restrict__ rstd, float cnt)
{
    const int c = blockIdx.x, t = threadIdx.x;
    __shared__ float rs[256], rq[256];
    rs[t] = p1[(long)c * 256 + t];
    rq[t] = p2[(long)c * 256 + t];
    __syncthreads();
    for (int st = 128; st > 0; st >>= 1) {
        if (t < st) { rs[t] += rs[t + st]; rq[t] += rq[t + st]; }
        __syncthreads();
    }
    if (t == 0) {
        const float m = rs[0] / cnt;
        mean[c] = m;
        rstd[c] = rsqrtf(rq[0] / cnt - m * m + 1e-5f);
    }
}

__global__ __launch_bounds__(256) void bn_apply_bf(
    const unsigned short* __restrict__ z, const float* __restrict__ x,
    const float* __restrict__ mean, const float* __restrict__ rstd,
    const float* __restrict__ gamma, const float* __restrict__ beta,
    float* __restrict__ out, int C, int N)
{
    const long i = ((long)blockIdx.x * 256 + threadIdx.x) * 8;
    const int c = (int)((i / N) % C);
    const float mu = mean[c], rs = rstd[c], ga = gamma[c], be = beta[c];
    const ushort4 z0 = *(const ushort4*)&z[i];
    const ushort4 z1 = *(const ushort4*)&z[i + 4];
    const float4 x0 = *(const float4*)&x[i];
    const float4 x1 = *(const float4*)&x[i + 4];
    float4 o0, o1;
    o0.x = (bf2f(z0.x) - mu) * rs * ga + be + x0.x;
    o0.y = (bf2f(z0.y) - mu) * rs * ga + be + x0.y;
    o0.z = (bf2f(z0.z) - mu) * rs * ga + be + x0.z;
    o0.w = (bf2f(z0.w) - mu) * rs * ga + be + x0.w;
    o1.x = (bf2f(z1.x) - mu) * rs * ga + be + x1.x;
    o1.y = (bf2f(z1.y) - mu) * rs * ga + be + x1.y;
    o1.z = (bf2f(z1.z) - mu) * rs * ga + be + x1.z;
    o1.w = (bf2f(z1.w) - mu) * rs * ga + be + x1.w;
    *(float4*)&out[i] = o0;
    *(float4*)&out[i + 4] = o1;
}

extern "C" void kernel_launch(void* const* d_in, const int* in_sizes, int n_in,
                              void* d_out, int out_size, void* d_ws, size_t ws_size,
                              hipStream_t stream)
{
    const int B = 8, C = 512, N = 2048, P = 256;
    const float* x      = (const float*)d_in[0];
    const float* Wg     = (const float*)d_in[1];
    const float* Wtheta = (const float*)d_in[2];
    const float* Wphi   = (const float*)d_in[3];
    const float* Wz     = (const float*)d_in[4];
    const float* gamma  = (const float*)d_in[5];
    const float* beta   = (const float*)d_in[6];
    float* out = (float*)d_out;

    // ---- workspace layout (float units) ----
    float* ws = (float*)d_ws;
    const long NCle = (long)N * C;            // 1,048,576 per batch (= N*2P)
    const long NP   = (long)N * P;            // 524,288 per batch
    const long R0   = (long)B * NCle;         // 8.39M floats
    const long BN   = (long)B * N;            // 16384
    unsigned short* xtH   = (unsigned short*)ws;                // B*N*C
    unsigned short* xtL   = xtH + B * NCle;
    unsigned short* zbf   = (unsigned short*)ws;                // aliases xt (dead)
    unsigned short* thphH = (unsigned short*)(ws + R0);         // B*N*2P
    unsigned short* thphL = thphH + B * NCle;                   // B*N*2P
    unsigned short* gbf   = (unsigned short*)(ws + 2 * R0);     // B*P*N
    unsigned short* fbf   = gbf + B * NP;                       // partials region
    unsigned short* ybf   = fbf + (long)B * N * N;              // B*N*P
    unsigned short* W2H   = ybf + B * NP;                       // 2P*C
    unsigned short* W2L   = W2H + 2L * P * C;
    unsigned short* WgB   = W2L + 2L * P * C;                   // P*C
    unsigned short* WzB   = WgB + (long)P * C;
    // split-K partials live in the (otherwise unused) fbf region: 8.65M floats
    float*          Opart = (float*)fbf;                        // [2][B*N][P]
    float*          Mpart = Opart + 2 * BN * (long)P;           // [2][B*N]
    float*          Lpart = Mpart + 2 * BN;                     // [2][B*N]
    // BN scratch aliases thph region (dead after fused_attn): [C][256] x2
    float*          bnp1  = ws + R0;
    float*          bnp2  = bnp1 + (long)C * 256;
    float*          mean  = bnp2 + (long)C * 256;
    float*          rstd  = mean + C;

    const long sX = (long)C * N;
    const int  P2 = 2 * P;

    // 1: transpose+split x -> xT hi/lo [B][N][C]
    transpose_split<<<dim3(N / 32, C / 32, B), 256, 0, stream>>>(x, xtH, xtL, C, N);
    // 2: weight preps
    split_w2<<<(2 * P * C + 255) / 256, 256, 0, stream>>>(Wtheta, Wphi, W2H, W2L, P * C);
    cast_bf16<<<P * C / 1024, 256, 0, stream>>>(Wg, WgB);
    cast_bf16<<<P * C / 1024, 256, 0, stream>>>(Wz, WzB);

    // 3: thph [B][N][2P] = xT @ W2^T (split in/out); 128x128, 512 blocks
    mfma_gemm<true, 2, 4, 4><<<dim3(P2 / 128, N / 128, B), 256, 0, stream>>>(
        xtH, xtL, W2H, W2L, thphH, thphL, C, C, C, P2, NCle, 0, NCle, nullptr, nullptr);
    // 4: g [B][P][N] = Wg @ xT^T (plain, bf16 out); 64x128, 512 blocks
    mfma_gemm<false, 1, 2, 4><<<dim3(N / 128, P / 64, B), 256, 0, stream>>>(
        WgB, WgB, xtH, xtH, gbf, gbf, C, C, C, N, 0, NCle, NP, nullptr, nullptr);

    // 5: fused attention, split-K over 2 key-halves (512 blocks, 2 blocks/CU)
    fused_attn<<<dim3(512), 256, 0, stream>>>(thphH, thphL, gbf, Opart, Mpart, Lpart);
    // 5b: deterministic flash merge -> yT [B][N][P] bf16
    merge_y<<<dim3((int)(BN / 8)), 256, 0, stream>>>(Opart, Mpart, Lpart, ybf);

    // 6: z [B][C][N] bf16 = Wz @ yT^T, BN partials (thph dead now)
    mfma_gemm<false, 3, 4, 4><<<dim3(N / 128, C / 128, B), 256, 0, stream>>>(
        WzB, WzB, ybf, ybf, zbf, zbf, P, P, P, N, 0, NP, sX, bnp1, bnp2);

    // 7: BN finalize + apply + residual
    bn_finalize<<<C, 256, 0, stream>>>(bnp1, bnp2, mean, rstd, (float)B * N);
    bn_apply_bf<<<(int)((B * sX) / 2048), 256, 0, stream>>>(zbf, x, mean, rstd, gamma, beta, out, C, N);
}